// Round 4
// baseline (1537.245 us; speedup 1.0000x reference)
//
#include <hip/hip_runtime.h>

#define TSTEPS 128
#define BATCH  4096
#define WPB    16      // waves per block (block = 1024 threads)

// LDS float-offset layout (all weights stored TRANSPOSED: WT[j][i] = W[i][j])
#define OFF_WTIN 0              // 64x64   -> [0,4096)
#define OFF_WT1  4096           // 64x32   -> [4096,6144)
#define OFF_WTH  6144           // 6 x 32x32 -> [6144,12288)
#define OFF_WTA  12288          // 32x400  -> [12288,25088)
#define OFF_WC   25088          // 32      -> [25088,25120)
#define OFF_TAB  25120          // 101-entry sequential 0.01f sum table
#define OFF_XBUF 25224          // 16 waves x 64 floats
#define LDS_FLOATS (OFF_XBUF + WPB * 64)
#define LDS_BYTES  (LDS_FLOATS * 4)

// strict-f32 LIF: reset uses PREVIOUS mem; op order ((beta*m)+cur)-(reset*thr),
// each op rounded separately (numpy semantics; intrinsics block fp-contract)
#define LIF(M, CUR, BETA, THR) {                                           \
    float r_ = ((M) > (THR)) ? (THR) : 0.0f;                               \
    (M) = __fsub_rn(__fadd_rn(__fmul_rn((BETA), (M)), (CUR)), r_); }

// dense spike dot: ascending j, fmaf(s_j, w_j, acc); s_j uniform -> SALU select.
// Bit-identical to the sequential __fadd_rn chain over set bits (fma(1,w,a)
// == fadd_rn(a,w); fma(0,w,a) == a exactly; acc starts +0, stays not -0).
#define DDOT32(MASK, COLP, OUTV) {                                         \
    float acc_ = 0.0f;                                                     \
    _Pragma("unroll")                                                      \
    for (int j_ = 0; j_ < 32; ++j_) {                                      \
      float sj_ = (((MASK) >> j_) & 1u) ? 1.0f : 0.0f;                     \
      acc_ = __builtin_fmaf(sj_, (COLP)[j_ * 32], acc_);                   \
    }                                                                      \
    OUTV = acc_; }

extern "C" __global__ __launch_bounds__(1024, 1)
void snn_actor_critic(const float* __restrict__ inputs,
                      const float* __restrict__ Win, const float* __restrict__ bin_,
                      const float* __restrict__ W1,  const float* __restrict__ b1,
                      const float* __restrict__ W2,  const float* __restrict__ b2,
                      const float* __restrict__ W3,  const float* __restrict__ b3,
                      const float* __restrict__ W4,  const float* __restrict__ b4,
                      const float* __restrict__ W5,  const float* __restrict__ b5,
                      const float* __restrict__ W6,  const float* __restrict__ b6,
                      const float* __restrict__ W7,  const float* __restrict__ b7,
                      const float* __restrict__ Wa,  const float* __restrict__ ba,
                      const float* __restrict__ Wc,  const float* __restrict__ bc,
                      const float* __restrict__ betac, const float* __restrict__ am,
                      float* __restrict__ out)
{
  extern __shared__ float lds[];
  const int tid  = threadIdx.x;
  const int lane = tid & 63;
  const int l32  = lane & 31;

  // ---- stage transposed weights into LDS ----
  #pragma unroll
  for (int it = 0; it < 4; ++it) {          // W_in 64x64
    int idx = tid + it * 1024; int i = idx >> 6, j = idx & 63;
    lds[OFF_WTIN + j * 64 + i] = Win[idx];
  }
  #pragma unroll
  for (int it = 0; it < 2; ++it) {          // W1 32x64
    int idx = tid + it * 1024; int i = idx >> 6, j = idx & 63;
    lds[OFF_WT1 + j * 32 + i] = W1[idx];
  }
  {                                         // W2..W7 32x32 each
    int i = tid >> 5, j = tid & 31; int d = j * 32 + i;
    lds[OFF_WTH + 0 * 1024 + d] = W2[tid];
    lds[OFF_WTH + 1 * 1024 + d] = W3[tid];
    lds[OFF_WTH + 2 * 1024 + d] = W4[tid];
    lds[OFF_WTH + 3 * 1024 + d] = W5[tid];
    lds[OFF_WTH + 4 * 1024 + d] = W6[tid];
    lds[OFF_WTH + 5 * 1024 + d] = W7[tid];
  }
  for (int idx = tid; idx < 12800; idx += 1024) {   // W_actor 400x32
    int k = idx >> 5, j = idx & 31;
    lds[OFF_WTA + j * 400 + k] = Wa[idx];
  }
  if (tid < 32) lds[OFF_WC + tid] = Wc[tid];
  if (tid == 0) {                           // sequential-sum table: n adds of 0.01f
    float a = 0.0f; lds[OFF_TAB] = 0.0f; float step = am[0];
    for (int n = 1; n <= 100; ++n) { a = __fadd_rn(a, step); lds[OFF_TAB + n] = a; }
  }

  // ---- biases / consts into registers (f32) ----
  float bin_f = bin_[lane];
  float bh0 = b1[l32], bh1 = b2[l32], bh2 = b3[l32], bh3 = b4[l32],
        bh4 = b5[l32], bh5 = b6[l32], bh6 = b7[l32];
  float ba0 = ba[lane],       ba1 = ba[lane + 64],  ba2 = ba[lane + 128],
        ba3 = ba[lane + 192], ba4 = ba[lane + 256], ba5 = ba[lane + 320],
        ba6 = (lane < 16) ? ba[lane + 384] : 0.0f;
  float bc_f    = bc[0];
  float beta_cf = betac[0];

  __syncthreads();

  // ---- per-wave batch element ----
  const int  wave = tid >> 6;
  const long b    = (long)blockIdx.x * WPB + wave;
  float* xw = lds + OFF_XBUF + wave * 64;
  const float* wcol = lds + OFF_WTIN + lane;
  const float* col1 = lds + OFF_WT1  + l32;
  const float* colh = lds + OFF_WTH  + l32;
  const float* wab  = lds + OFF_WTA  + lane;
  const float* wcp  = lds + OFF_WC;
  const float* tab  = lds + OFF_TAB;
  const float* inp  = inputs + b * 64 + lane;
  float* vout = out + b;                                   // vals[t*B + b]
  float* aout = out + (long)TSTEPS * BATCH + b * 4 + lane; // actions[(t*B+b)*4 + a]

  float m_in = 0.0f;
  float mh0 = 0.0f, mh1 = 0.0f, mh2 = 0.0f, mh3 = 0.0f, mh4 = 0.0f, mh5 = 0.0f, mh6 = 0.0f;
  float ma0 = 0.0f, ma1 = 0.0f, ma2 = 0.0f, ma3 = 0.0f, ma4 = 0.0f, ma5 = 0.0f, ma6 = 0.0f;
  float mc  = 0.0f;

  float xnext = inp[0];   // prefetch t=0

  for (int t = 0; t < TSTEPS; ++t) {
    xw[lane] = xnext;
    if (t + 1 < TSTEPS)                       // prefetch t+1: hides HBM latency
      xnext = inp[(long)(t + 1) * (BATCH * 64)];

    // ---- input layer: dense 64-dot, single ascending fma chain ----
    float acc = 0.0f;
    #pragma unroll
    for (int j = 0; j < 64; ++j)
      acc = __builtin_fmaf(xw[j], wcol[j * 64], acc);
    float cur = __fadd_rn(acc, bin_f);
    LIF(m_in, cur, 0.65f, 0.25f);
    unsigned long long s64 = __ballot(__fsub_rn(m_in, 0.25f) > 0.0f);

    // ---- L1: 64-bit spike mask -> 32 outputs (lanes 32-63 mirror 0-31) ----
    float d1 = 0.0f;
    #pragma unroll
    for (int j = 0; j < 64; ++j) {
      float sj = ((s64 >> j) & 1ULL) ? 1.0f : 0.0f;
      d1 = __builtin_fmaf(sj, col1[j * 32], d1);
    }
    float cur1 = __fadd_rn(d1, bh0);
    LIF(mh0, cur1, 0.65f, 0.25f);
    unsigned k1 = (unsigned)__ballot(__fsub_rn(mh0, 0.25f) > 0.0f);

    // ---- L2..L7: dense 32 ----
    float d2; DDOT32(k1, colh + 0 * 1024, d2);
    float cur2 = __fadd_rn(d2, bh1);
    LIF(mh1, cur2, 0.85f, 1.0f);
    unsigned k2 = (unsigned)__ballot(__fsub_rn(mh1, 1.0f) > 0.0f);

    float d3; DDOT32(k2, colh + 1 * 1024, d3);
    float cur3 = __fadd_rn(d3, bh2);
    LIF(mh2, cur3, 0.85f, 1.0f);
    unsigned k3 = (unsigned)__ballot(__fsub_rn(mh2, 1.0f) > 0.0f);

    float d4; DDOT32(k3, colh + 2 * 1024, d4);
    float cur4 = __fadd_rn(d4, bh3);
    LIF(mh3, cur4, 0.95f, 1.0f);
    unsigned k4 = (unsigned)__ballot(__fsub_rn(mh3, 1.0f) > 0.0f);

    float d5; DDOT32(k4, colh + 3 * 1024, d5);
    float cur5 = __fadd_rn(d5, bh4);
    LIF(mh4, cur5, 0.95f, 1.0f);
    unsigned k5 = (unsigned)__ballot(__fsub_rn(mh4, 1.0f) > 0.0f);

    float d6; DDOT32(k5, colh + 4 * 1024, d6);
    float cur6 = __fadd_rn(d6, bh5);
    LIF(mh5, cur6, 0.95f, 1.0f);
    unsigned k6 = (unsigned)__ballot(__fsub_rn(mh5, 1.0f) > 0.0f);

    float d7; DDOT32(k6, colh + 5 * 1024, d7);
    float cur7 = __fadd_rn(d7, bh6);
    LIF(mh6, cur7, 0.95f, 1.0f);
    unsigned k7 = (unsigned)__ballot(__fsub_rn(mh6, 1.0f) > 0.0f);

    // ---- actor: dense, 7 independent chains (lane handles k = lane + 64r) ----
    float ca0 = 0.0f, ca1 = 0.0f, ca2 = 0.0f, ca3 = 0.0f, ca4 = 0.0f, ca5 = 0.0f, ca6 = 0.0f;
    #pragma unroll
    for (int j = 0; j < 32; ++j) {
      float sj = ((k7 >> j) & 1u) ? 1.0f : 0.0f;
      const float* rp = wab + j * 400;
      ca0 = __builtin_fmaf(sj, rp[0],   ca0);
      ca1 = __builtin_fmaf(sj, rp[64],  ca1);
      ca2 = __builtin_fmaf(sj, rp[128], ca2);
      ca3 = __builtin_fmaf(sj, rp[192], ca3);
      ca4 = __builtin_fmaf(sj, rp[256], ca4);
      ca5 = __builtin_fmaf(sj, rp[320], ca5);
      ca6 = __builtin_fmaf(sj, rp[384], ca6);   // garbage for lane>=16; masked below
    }
    float cua0 = __fadd_rn(ca0, ba0), cua1 = __fadd_rn(ca1, ba1),
          cua2 = __fadd_rn(ca2, ba2), cua3 = __fadd_rn(ca3, ba3),
          cua4 = __fadd_rn(ca4, ba4), cua5 = __fadd_rn(ca5, ba5),
          cua6 = __fadd_rn(ca6, ba6);
    unsigned long long sa0, sa1, sa2, sa3, sa4, sa5, sa6;
    LIF(ma0, cua0, 0.95f, 1.0f); sa0 = __ballot(__fsub_rn(ma0, 1.0f) > 0.0f);
    LIF(ma1, cua1, 0.95f, 1.0f); sa1 = __ballot(__fsub_rn(ma1, 1.0f) > 0.0f);
    LIF(ma2, cua2, 0.95f, 1.0f); sa2 = __ballot(__fsub_rn(ma2, 1.0f) > 0.0f);
    LIF(ma3, cua3, 0.95f, 1.0f); sa3 = __ballot(__fsub_rn(ma3, 1.0f) > 0.0f);
    LIF(ma4, cua4, 0.95f, 1.0f); sa4 = __ballot(__fsub_rn(ma4, 1.0f) > 0.0f);
    LIF(ma5, cua5, 0.95f, 1.0f); sa5 = __ballot(__fsub_rn(ma5, 1.0f) > 0.0f);
    LIF(ma6, cua6, 0.95f, 1.0f); sa6 = __ballot(__fsub_rn(ma6, 1.0f) > 0.0f);

    // group counts (actor neuron k = 64r + bit; group = k/100)
    int c0 = __popcll(sa0) + __popcll(sa1 & 0xFFFFFFFFFULL);
    int c1 = __popcll(sa1 >> 36) + __popcll(sa2) + __popcll(sa3 & 0xFFULL);
    int c2 = __popcll(sa3 >> 8) + __popcll(sa4 & 0xFFFFFFFFFFFULL);
    int c3 = __popcll(sa4 >> 44) + __popcll(sa5) + __popcll(sa6 & 0xFFFFULL);

    // ---- critic: dense 32, broadcast reads (all lanes identical) ----
    float cc = 0.0f;
    #pragma unroll
    for (int j = 0; j < 32; ++j) {
      float sj = ((k7 >> j) & 1u) ? 1.0f : 0.0f;
      cc = __builtin_fmaf(sj, wcp[j], cc);
    }
    float curc = __fadd_rn(cc, bc_f);
    LIF(mc, curc, beta_cf, 100.0f);

    // ---- outputs ----
    if (lane == 0) vout[(long)t * BATCH] = mc;
    if (lane < 4) {
      int cnt = (lane == 0) ? c0 : (lane == 1) ? c1 : (lane == 2) ? c2 : c3;
      aout[(long)t * BATCH * 4] = tab[cnt];  // n sequential adds of 0.01f
    }
  }
}

extern "C" void kernel_launch(void* const* d_in, const int* in_sizes, int n_in,
                              void* d_out, int out_size, void* d_ws, size_t ws_size,
                              hipStream_t stream) {
  (void)in_sizes; (void)n_in; (void)out_size; (void)d_ws; (void)ws_size;
  hipFuncSetAttribute((const void*)snn_actor_critic,
                      hipFuncAttributeMaxDynamicSharedMemorySize, LDS_BYTES);
  const float* I    = (const float*)d_in[0];
  const float* Win  = (const float*)d_in[1];  const float* bin_ = (const float*)d_in[2];
  const float* W1   = (const float*)d_in[3];  const float* b1   = (const float*)d_in[4];
  const float* W2   = (const float*)d_in[5];  const float* b2   = (const float*)d_in[6];
  const float* W3   = (const float*)d_in[7];  const float* b3   = (const float*)d_in[8];
  const float* W4   = (const float*)d_in[9];  const float* b4   = (const float*)d_in[10];
  const float* W5   = (const float*)d_in[11]; const float* b5   = (const float*)d_in[12];
  const float* W6   = (const float*)d_in[13]; const float* b6   = (const float*)d_in[14];
  const float* W7   = (const float*)d_in[15]; const float* b7   = (const float*)d_in[16];
  const float* Wa   = (const float*)d_in[17]; const float* ba   = (const float*)d_in[18];
  const float* Wc   = (const float*)d_in[19]; const float* bc   = (const float*)d_in[20];
  const float* betc = (const float*)d_in[21]; const float* am   = (const float*)d_in[22];
  float* out = (float*)d_out;

  snn_actor_critic<<<dim3(BATCH / WPB), dim3(1024), LDS_BYTES, stream>>>(
      I, Win, bin_, W1, b1, W2, b2, W3, b3, W4, b4, W5, b5, W6, b6, W7, b7,
      Wa, ba, Wc, bc, betc, am, out);
}

// Round 5
// 1323.205 us; speedup vs baseline: 1.1618x; 1.1618x over previous
//
#include <hip/hip_runtime.h>

#define TSTEPS 128
#define BATCH  4096
#define WPB    8       // waves per block (512 threads), 2 batch elements per wave

typedef float f32x2 __attribute__((ext_vector_type(2)));
typedef unsigned long long u64;

// ---- LDS layout in float2 units ----
#define O2_WIN 0        // [32 jp][64 l]        -> 2048
#define O2_W1  2048     // [32 jp][32 i]        -> 1024
#define O2_WH  3072     // 6 x [16 jp][32 i]    -> 3072
#define O2_WA  6144     // [7 r][16 jp][64 l]   -> 7168
#define O2_WC  13312    // [16 jp]              -> 16
#define O2_X   13328    // 8 waves x [64 j]     -> 512
#define TABF   27680    // float offset of 101-entry table
#define LDS_FLOATS (TABF + 104)
#define LDS_BYTES  (LDS_FLOATS * 4)

// packed sel constants: {el0, el1} halves, 1.0f bit patterns
#define C00 0ull
#define C10 0x3f800000ull
#define C01 (0x3f800000ull << 32)
#define C11 (0x3f800000ull | (0x3f800000ull << 32))

// uniform packed select for bit J of masks M0 (el0), M1 (el1) -> SALU cselects
#define SEL2(M0, M1, J)                                                    \
  ((((M0) >> (J)) & 1u) ? ((((M1) >> (J)) & 1u) ? C11 : C10)               \
                        : ((((M1) >> (J)) & 1u) ? C01 : C00))

// v_pk_fma_f32: per-half IEEE f32 fma (bit-identical to scalar fmaf chains).
// _S*: src0 = packed sel (SGPR pair), src1 = weight pair, LO/HI half broadcast.
// _V*: src0 = packed value pair (VGPR), src1 = weight pair, LO/HI broadcast.
#define PKFMA_SLO(ACC, SEL, W2)                                            \
  asm("v_pk_fma_f32 %0, %1, %2, %0 op_sel:[0,0,0] op_sel_hi:[1,0,1]"       \
      : "+v"(ACC) : "s"(SEL), "v"(W2))
#define PKFMA_SHI(ACC, SEL, W2)                                            \
  asm("v_pk_fma_f32 %0, %1, %2, %0 op_sel:[0,1,0] op_sel_hi:[1,1,1]"       \
      : "+v"(ACC) : "s"(SEL), "v"(W2))
#define PKFMA_VLO(ACC, XY, W2)                                             \
  asm("v_pk_fma_f32 %0, %1, %2, %0 op_sel:[0,0,0] op_sel_hi:[1,0,1]"       \
      : "+v"(ACC) : "v"(XY), "v"(W2))
#define PKFMA_VHI(ACC, XY, W2)                                             \
  asm("v_pk_fma_f32 %0, %1, %2, %0 op_sel:[0,1,0] op_sel_hi:[1,1,1]"       \
      : "+v"(ACC) : "v"(XY), "v"(W2))

// strict-f32 LIF per half: reset uses PREVIOUS mem; ((beta*m)+cur)-r, each op rounded
#define LIF2(M, CX, CY, BETA, THR) {                                       \
    float rx_ = (M[0] > (THR)) ? (THR) : 0.0f;                             \
    float ry_ = (M[1] > (THR)) ? (THR) : 0.0f;                             \
    M[0] = __fsub_rn(__fadd_rn(__fmul_rn((BETA), M[0]), (CX)), rx_);       \
    M[1] = __fsub_rn(__fadd_rn(__fmul_rn((BETA), M[1]), (CY)), ry_); }

// LIF + per-element ballots -> uniform 32-bit masks in SGPRs
#define SPIKES32(M, ACC, BIAS, BETA, THR, M0, M1) {                        \
    float cx_ = __fadd_rn(ACC[0], (BIAS));                                 \
    float cy_ = __fadd_rn(ACC[1], (BIAS));                                 \
    LIF2(M, cx_, cy_, BETA, THR);                                          \
    u64 b0_ = __ballot(__fsub_rn(M[0], (THR)) > 0.0f);                     \
    u64 b1_ = __ballot(__fsub_rn(M[1], (THR)) > 0.0f);                     \
    M0 = __builtin_amdgcn_readfirstlane((unsigned)b0_);                    \
    M1 = __builtin_amdgcn_readfirstlane((unsigned)b1_); }

// dense 32-input spike layer: paired-j b64 weight reads + 2 pk-FMAs per pair
#define DENSE32_PK(ACC, BASE2, M0, M1) {                                   \
    _Pragma("unroll")                                                      \
    for (int jp_ = 0; jp_ < 16; ++jp_) {                                   \
      f32x2 w2_ = (BASE2)[jp_ * 32 + i32];                                 \
      u64 sA_ = SEL2(M0, M1, 2 * jp_);                                     \
      u64 sB_ = SEL2(M0, M1, 2 * jp_ + 1);                                 \
      PKFMA_SLO(ACC, sA_, w2_);                                            \
      PKFMA_SHI(ACC, sB_, w2_);                                            \
    } }

extern "C" __global__ __launch_bounds__(512, 1)
void snn_actor_critic(const float* __restrict__ inputs,
                      const float* __restrict__ Win, const float* __restrict__ bin_,
                      const float* __restrict__ W1,  const float* __restrict__ b1,
                      const float* __restrict__ W2,  const float* __restrict__ b2,
                      const float* __restrict__ W3,  const float* __restrict__ b3,
                      const float* __restrict__ W4,  const float* __restrict__ b4,
                      const float* __restrict__ W5,  const float* __restrict__ b5,
                      const float* __restrict__ W6,  const float* __restrict__ b6,
                      const float* __restrict__ W7,  const float* __restrict__ b7,
                      const float* __restrict__ Wa,  const float* __restrict__ ba,
                      const float* __restrict__ Wc,  const float* __restrict__ bc,
                      const float* __restrict__ betac, const float* __restrict__ am,
                      float* __restrict__ out)
{
  extern __shared__ float lds[];
  f32x2* lds2 = (f32x2*)lds;
  const int tid  = threadIdx.x;
  const int lane = tid & 63;
  const int i32  = lane & 31;

  // ---- stage paired-j (float2) weight layouts ----
  #pragma unroll
  for (int it = 0; it < 4; ++it) {                    // Win: [jp][l]
    int e = tid + it * 512; int jp = e >> 6, l = e & 63;
    lds2[O2_WIN + e] = (f32x2){Win[l * 64 + 2 * jp], Win[l * 64 + 2 * jp + 1]};
  }
  #pragma unroll
  for (int it = 0; it < 2; ++it) {                    // W1: [jp][i]
    int e = tid + it * 512; int jp = e >> 5, i = e & 31;
    lds2[O2_W1 + e] = (f32x2){W1[i * 64 + 2 * jp], W1[i * 64 + 2 * jp + 1]};
  }
  {                                                   // W2..W7: [jp][i], 512 each
    int jp = tid >> 5, i = tid & 31;
    lds2[O2_WH + 0 * 512 + tid] = (f32x2){W2[i * 32 + 2 * jp], W2[i * 32 + 2 * jp + 1]};
    lds2[O2_WH + 1 * 512 + tid] = (f32x2){W3[i * 32 + 2 * jp], W3[i * 32 + 2 * jp + 1]};
    lds2[O2_WH + 2 * 512 + tid] = (f32x2){W4[i * 32 + 2 * jp], W4[i * 32 + 2 * jp + 1]};
    lds2[O2_WH + 3 * 512 + tid] = (f32x2){W5[i * 32 + 2 * jp], W5[i * 32 + 2 * jp + 1]};
    lds2[O2_WH + 4 * 512 + tid] = (f32x2){W6[i * 32 + 2 * jp], W6[i * 32 + 2 * jp + 1]};
    lds2[O2_WH + 5 * 512 + tid] = (f32x2){W7[i * 32 + 2 * jp], W7[i * 32 + 2 * jp + 1]};
  }
  for (int e = tid; e < 7168; e += 512) {             // W_actor: [r][jp][l]
    int r = e >> 10, rem = e & 1023, jp = rem >> 6, l = rem & 63;
    int k = r * 64 + l;
    lds2[O2_WA + e] = (k < 400)
        ? (f32x2){Wa[k * 32 + 2 * jp], Wa[k * 32 + 2 * jp + 1]}
        : (f32x2){0.0f, 0.0f};
  }
  if (tid < 16) lds2[O2_WC + tid] = (f32x2){Wc[2 * tid], Wc[2 * tid + 1]};
  if (tid == 0) {                                     // sequential 0.01f sum table
    float a = 0.0f; lds[TABF] = 0.0f; float step = am[0];
    for (int n = 1; n <= 100; ++n) { a = __fadd_rn(a, step); lds[TABF + n] = a; }
  }

  // ---- biases / consts (shared by both packed elements) ----
  float bin_f = bin_[lane];
  float bh0 = b1[i32], bh1 = b2[i32], bh2 = b3[i32], bh3 = b4[i32],
        bh4 = b5[i32], bh5 = b6[i32], bh6 = b7[i32];
  float bA0 = ba[lane],       bA1 = ba[lane + 64],  bA2 = ba[lane + 128],
        bA3 = ba[lane + 192], bA4 = ba[lane + 256], bA5 = ba[lane + 320],
        bA6 = (lane < 16) ? ba[lane + 384] : 0.0f;
  float bc_f = bc[0];
  float beta_cf = betac[0];

  __syncthreads();

  // ---- per-wave: 2 batch elements ----
  const int  wave = tid >> 6;
  const long gw   = (long)blockIdx.x * WPB + wave;
  const long e0   = gw * 2;                 // e1 = e0 + 1
  const f32x2* winb = lds2 + O2_WIN;        // + jp*64 + lane
  const f32x2* w1b  = lds2 + O2_W1;         // + jp*32 + i32
  const f32x2* whb  = lds2 + O2_WH;         // + L*512 + jp*32 + i32
  const f32x2* wab  = lds2 + O2_WA;         // + r*1024 + jp*64 + lane
  const f32x2* wcb  = lds2 + O2_WC;         // + jp (broadcast)
  const f32x2* xw2  = lds2 + O2_X + wave * 64;
  f32x2* xw2w = lds2 + O2_X + wave * 64;
  const float* tab  = lds + TABF;
  const float* inp0 = inputs + e0 * 64 + lane;
  const float* inp1 = inputs + (e0 + 1) * 64 + lane;
  float* vout = out + e0;                                    // vals[t*B + e]
  float* aout = out + (long)TSTEPS * BATCH + e0 * 4;         // actions[(t*B+e)*4+g]

  f32x2 mI = {0,0};
  f32x2 m1 = {0,0}, m2 = {0,0}, m3 = {0,0}, m4 = {0,0}, m5 = {0,0}, m6 = {0,0}, m7 = {0,0};
  f32x2 A0 = {0,0}, A1 = {0,0}, A2 = {0,0}, A3 = {0,0}, A4 = {0,0}, A5 = {0,0}, A6 = {0,0};
  f32x2 mc = {0,0};

  float xn0 = inp0[0], xn1 = inp1[0];       // prefetch t=0

  for (int t = 0; t < TSTEPS; ++t) {
    xw2w[lane] = (f32x2){xn0, xn1};
    if (t + 1 < TSTEPS) {                   // prefetch t+1 (hides HBM latency)
      xn0 = inp0[(long)(t + 1) * (BATCH * 64)];
      xn1 = inp1[(long)(t + 1) * (BATCH * 64)];
    }

    // ---- input layer: dense 64-dot, packed over 2 elements ----
    f32x2 aI = {0,0};
    #pragma unroll
    for (int jp = 0; jp < 32; ++jp) {
      f32x2 w2 = winb[jp * 64 + lane];
      f32x2 xa = xw2[2 * jp];
      f32x2 xb = xw2[2 * jp + 1];
      PKFMA_VLO(aI, xa, w2);
      PKFMA_VHI(aI, xb, w2);
    }
    {
      float cx = __fadd_rn(aI[0], bin_f), cy = __fadd_rn(aI[1], bin_f);
      LIF2(mI, cx, cy, 0.65f, 0.25f);
    }
    u64 ib0 = __ballot(__fsub_rn(mI[0], 0.25f) > 0.0f);
    u64 ib1 = __ballot(__fsub_rn(mI[1], 0.25f) > 0.0f);
    unsigned s0lo = __builtin_amdgcn_readfirstlane((unsigned)ib0);
    unsigned s0hi = __builtin_amdgcn_readfirstlane((unsigned)(ib0 >> 32));
    unsigned s1lo = __builtin_amdgcn_readfirstlane((unsigned)ib1);
    unsigned s1hi = __builtin_amdgcn_readfirstlane((unsigned)(ib1 >> 32));

    // ---- L1: 64 inputs (two 32-bit halves), 32 outputs ----
    f32x2 a1 = {0,0};
    DENSE32_PK(a1, w1b, s0lo, s1lo);
    DENSE32_PK(a1, w1b + 16 * 32, s0hi, s1hi);
    unsigned k1a, k1b; SPIKES32(m1, a1, bh0, 0.65f, 0.25f, k1a, k1b);

    // ---- L2..L7 ----
    f32x2 a2 = {0,0}; DENSE32_PK(a2, whb + 0 * 512, k1a, k1b);
    unsigned k2a, k2b; SPIKES32(m2, a2, bh1, 0.85f, 1.0f, k2a, k2b);
    f32x2 a3 = {0,0}; DENSE32_PK(a3, whb + 1 * 512, k2a, k2b);
    unsigned k3a, k3b; SPIKES32(m3, a3, bh2, 0.85f, 1.0f, k3a, k3b);
    f32x2 a4 = {0,0}; DENSE32_PK(a4, whb + 2 * 512, k3a, k3b);
    unsigned k4a, k4b; SPIKES32(m4, a4, bh3, 0.95f, 1.0f, k4a, k4b);
    f32x2 a5 = {0,0}; DENSE32_PK(a5, whb + 3 * 512, k4a, k4b);
    unsigned k5a, k5b; SPIKES32(m5, a5, bh4, 0.95f, 1.0f, k5a, k5b);
    f32x2 a6 = {0,0}; DENSE32_PK(a6, whb + 4 * 512, k5a, k5b);
    unsigned k6a, k6b; SPIKES32(m6, a6, bh5, 0.95f, 1.0f, k6a, k6b);
    f32x2 a7 = {0,0}; DENSE32_PK(a7, whb + 5 * 512, k6a, k6b);
    unsigned k7a, k7b; SPIKES32(m7, a7, bh6, 0.95f, 1.0f, k7a, k7b);

    // ---- actor (7 row-accs) + critic folded in one sweep over jp ----
    f32x2 c0 = {0,0}, c1 = {0,0}, c2 = {0,0}, c3 = {0,0},
          c4 = {0,0}, c5 = {0,0}, c6 = {0,0}, cc = {0,0};
    #pragma unroll
    for (int jp = 0; jp < 16; ++jp) {
      u64 sA = SEL2(k7a, k7b, 2 * jp);
      u64 sB = SEL2(k7a, k7b, 2 * jp + 1);
      f32x2 w0 = wab[0 * 1024 + jp * 64 + lane];
      f32x2 w1v = wab[1 * 1024 + jp * 64 + lane];
      f32x2 w2v = wab[2 * 1024 + jp * 64 + lane];
      f32x2 w3v = wab[3 * 1024 + jp * 64 + lane];
      f32x2 w4v = wab[4 * 1024 + jp * 64 + lane];
      f32x2 w5v = wab[5 * 1024 + jp * 64 + lane];
      f32x2 w6v = wab[6 * 1024 + jp * 64 + lane];
      f32x2 wcv = wcb[jp];
      PKFMA_SLO(c0, sA, w0);  PKFMA_SHI(c0, sB, w0);
      PKFMA_SLO(c1, sA, w1v); PKFMA_SHI(c1, sB, w1v);
      PKFMA_SLO(c2, sA, w2v); PKFMA_SHI(c2, sB, w2v);
      PKFMA_SLO(c3, sA, w3v); PKFMA_SHI(c3, sB, w3v);
      PKFMA_SLO(c4, sA, w4v); PKFMA_SHI(c4, sB, w4v);
      PKFMA_SLO(c5, sA, w5v); PKFMA_SHI(c5, sB, w5v);
      PKFMA_SLO(c6, sA, w6v); PKFMA_SHI(c6, sB, w6v);
      PKFMA_SLO(cc, sA, wcv); PKFMA_SHI(cc, sB, wcv);
    }
    // actor LIFs + per-element ballots
    u64 sa0, sa1, sa2, sa3, sa4, sa5, sa6;   // el0
    u64 ta0, ta1, ta2, ta3, ta4, ta5, ta6;   // el1
    {
      float cx, cy;
      cx = __fadd_rn(c0[0], bA0); cy = __fadd_rn(c0[1], bA0);
      LIF2(A0, cx, cy, 0.95f, 1.0f);
      sa0 = __ballot(__fsub_rn(A0[0], 1.0f) > 0.0f);
      ta0 = __ballot(__fsub_rn(A0[1], 1.0f) > 0.0f);
      cx = __fadd_rn(c1[0], bA1); cy = __fadd_rn(c1[1], bA1);
      LIF2(A1, cx, cy, 0.95f, 1.0f);
      sa1 = __ballot(__fsub_rn(A1[0], 1.0f) > 0.0f);
      ta1 = __ballot(__fsub_rn(A1[1], 1.0f) > 0.0f);
      cx = __fadd_rn(c2[0], bA2); cy = __fadd_rn(c2[1], bA2);
      LIF2(A2, cx, cy, 0.95f, 1.0f);
      sa2 = __ballot(__fsub_rn(A2[0], 1.0f) > 0.0f);
      ta2 = __ballot(__fsub_rn(A2[1], 1.0f) > 0.0f);
      cx = __fadd_rn(c3[0], bA3); cy = __fadd_rn(c3[1], bA3);
      LIF2(A3, cx, cy, 0.95f, 1.0f);
      sa3 = __ballot(__fsub_rn(A3[0], 1.0f) > 0.0f);
      ta3 = __ballot(__fsub_rn(A3[1], 1.0f) > 0.0f);
      cx = __fadd_rn(c4[0], bA4); cy = __fadd_rn(c4[1], bA4);
      LIF2(A4, cx, cy, 0.95f, 1.0f);
      sa4 = __ballot(__fsub_rn(A4[0], 1.0f) > 0.0f);
      ta4 = __ballot(__fsub_rn(A4[1], 1.0f) > 0.0f);
      cx = __fadd_rn(c5[0], bA5); cy = __fadd_rn(c5[1], bA5);
      LIF2(A5, cx, cy, 0.95f, 1.0f);
      sa5 = __ballot(__fsub_rn(A5[0], 1.0f) > 0.0f);
      ta5 = __ballot(__fsub_rn(A5[1], 1.0f) > 0.0f);
      cx = __fadd_rn(c6[0], bA6); cy = __fadd_rn(c6[1], bA6);
      LIF2(A6, cx, cy, 0.95f, 1.0f);
      sa6 = __ballot(__fsub_rn(A6[0], 1.0f) > 0.0f);
      ta6 = __ballot(__fsub_rn(A6[1], 1.0f) > 0.0f);
    }
    // group counts (neuron k = 64r + bit, group = k/100), per element
    int g0 = __popcll(sa0) + __popcll(sa1 & 0xFFFFFFFFFULL);
    int g1 = __popcll(sa1 >> 36) + __popcll(sa2) + __popcll(sa3 & 0xFFULL);
    int g2 = __popcll(sa3 >> 8) + __popcll(sa4 & 0xFFFFFFFFFFFULL);
    int g3 = __popcll(sa4 >> 44) + __popcll(sa5) + __popcll(sa6 & 0xFFFFULL);
    int h0 = __popcll(ta0) + __popcll(ta1 & 0xFFFFFFFFFULL);
    int h1 = __popcll(ta1 >> 36) + __popcll(ta2) + __popcll(ta3 & 0xFFULL);
    int h2 = __popcll(ta3 >> 8) + __popcll(ta4 & 0xFFFFFFFFFFFULL);
    int h3 = __popcll(ta4 >> 44) + __popcll(ta5) + __popcll(ta6 & 0xFFFFULL);

    // ---- critic LIF ----
    {
      float cx = __fadd_rn(cc[0], bc_f), cy = __fadd_rn(cc[1], bc_f);
      LIF2(mc, cx, cy, beta_cf, 100.0f);
    }

    // ---- outputs ----
    if (lane < 2) vout[(long)t * BATCH + lane] = (lane ? mc[1] : mc[0]);
    if (lane < 8) {
      int g = lane & 3;
      int cnt = (lane >= 4) ? (g == 0 ? h0 : g == 1 ? h1 : g == 2 ? h2 : h3)
                            : (g == 0 ? g0 : g == 1 ? g1 : g == 2 ? g2 : g3);
      aout[(long)t * (BATCH * 4) + lane] = tab[cnt];
    }
  }
}

extern "C" void kernel_launch(void* const* d_in, const int* in_sizes, int n_in,
                              void* d_out, int out_size, void* d_ws, size_t ws_size,
                              hipStream_t stream) {
  (void)in_sizes; (void)n_in; (void)out_size; (void)d_ws; (void)ws_size;
  hipFuncSetAttribute((const void*)snn_actor_critic,
                      hipFuncAttributeMaxDynamicSharedMemorySize, LDS_BYTES);
  const float* I    = (const float*)d_in[0];
  const float* Win  = (const float*)d_in[1];  const float* bin_ = (const float*)d_in[2];
  const float* W1   = (const float*)d_in[3];  const float* b1   = (const float*)d_in[4];
  const float* W2   = (const float*)d_in[5];  const float* b2   = (const float*)d_in[6];
  const float* W3   = (const float*)d_in[7];  const float* b3   = (const float*)d_in[8];
  const float* W4   = (const float*)d_in[9];  const float* b4   = (const float*)d_in[10];
  const float* W5   = (const float*)d_in[11]; const float* b5   = (const float*)d_in[12];
  const float* W6   = (const float*)d_in[13]; const float* b6   = (const float*)d_in[14];
  const float* W7   = (const float*)d_in[15]; const float* b7   = (const float*)d_in[16];
  const float* Wa   = (const float*)d_in[17]; const float* ba   = (const float*)d_in[18];
  const float* Wc   = (const float*)d_in[19]; const float* bc   = (const float*)d_in[20];
  const float* betc = (const float*)d_in[21]; const float* am   = (const float*)d_in[22];
  float* out = (float*)d_out;

  snn_actor_critic<<<dim3(BATCH / (WPB * 2)), dim3(512), LDS_BYTES, stream>>>(
      I, Win, bin_, W1, b1, W2, b2, W3, b3, W4, b4, W5, b5, W6, b6, W7, b7,
      Wa, ba, Wc, bc, betc, am, out);
}

// Round 7
// 1070.785 us; speedup vs baseline: 1.4356x; 1.2357x over previous
//
#include <hip/hip_runtime.h>

#define TSTEPS 128
#define BATCH  4096

typedef float f32x2 __attribute__((ext_vector_type(2)));
typedef float f32x4 __attribute__((ext_vector_type(4)));
typedef unsigned long long u64;

// ---- LDS layout (f32 units) ----
#define OFF_WINQ 0        // [16 jq][64 l] f32x4          -> 4096
#define OFF_W1Q  4096     // [16 jq][32 i] f32x4          -> 2048
#define OFF_WHQ  6144     // 6 x [8 jq][32 i] f32x4       -> 6144
#define OFF_WAQ  12288    // [7 r][8 jq][64 l] f32x4      -> 14336
#define OFF_WCP  26624    // [16 jp] f32x2                -> 32
#define OFF_XP   26656    // 8 pairs x [64 j] f32x2       -> 1024
#define OFF_MSK  27680    // 2 slots x 8 pairs x uint2    -> 32
#define OFF_TAB  27712    // 101-entry sequential 0.01f sums
#define LDS_FLOATS 27816
#define LDS_BYTES  (LDS_FLOATS * 4)

// packed sel constants: {el0, el1} halves, 1.0f bit patterns
#define C00 0ull
#define C10 0x3f800000ull
#define C01 (0x3f800000ull << 32)
#define C11 (0x3f800000ull | (0x3f800000ull << 32))
// uniform packed select for bit J of masks M0 (el0), M1 (el1) -> SALU cselects
#define SEL2(M0, M1, J)                                                    \
  ((((M0) >> (J)) & 1u) ? ((((M1) >> (J)) & 1u) ? C11 : C10)               \
                        : ((((M1) >> (J)) & 1u) ? C01 : C00))

// v_pk_fma_f32: per-half IEEE f32 fma (bit-identical to scalar fmaf chains).
// ALL sources must be 64-bit pairs (VOP3P) — weight comes as an f32x2 pair,
// op_sel picks lo/hi half broadcast to both lanes of the accumulator.
#define PKFMA_SLO(ACC, SEL, W2)                                            \
  asm("v_pk_fma_f32 %0, %1, %2, %0 op_sel:[0,0,0] op_sel_hi:[1,0,1]"       \
      : "+v"(ACC) : "s"(SEL), "v"(W2))
#define PKFMA_SHI(ACC, SEL, W2)                                            \
  asm("v_pk_fma_f32 %0, %1, %2, %0 op_sel:[0,1,0] op_sel_hi:[1,1,1]"       \
      : "+v"(ACC) : "s"(SEL), "v"(W2))
#define PKFMA_VLO(ACC, XY, W2)                                             \
  asm("v_pk_fma_f32 %0, %1, %2, %0 op_sel:[0,0,0] op_sel_hi:[1,0,1]"       \
      : "+v"(ACC) : "v"(XY), "v"(W2))
#define PKFMA_VHI(ACC, XY, W2)                                             \
  asm("v_pk_fma_f32 %0, %1, %2, %0 op_sel:[0,1,0] op_sel_hi:[1,1,1]"       \
      : "+v"(ACC) : "v"(XY), "v"(W2))

// strict-f32 LIF per half: reset uses PREVIOUS mem; ((beta*m)+cur)-r per-op rounded
#define LIF2(M, CX, CY, BETA, THR) {                                       \
    float rx_ = (M[0] > (THR)) ? (THR) : 0.0f;                             \
    float ry_ = (M[1] > (THR)) ? (THR) : 0.0f;                             \
    M[0] = __fsub_rn(__fadd_rn(__fmul_rn((BETA), M[0]), (CX)), rx_);       \
    M[1] = __fsub_rn(__fadd_rn(__fmul_rn((BETA), M[1]), (CY)), ry_); }

// LIF + per-element ballots -> uniform 32-bit masks in SGPRs
#define SPIKES32(M, ACC, BIAS, BETA, THR, MA, MB) {                        \
    float cx_ = __fadd_rn(ACC[0], (BIAS));                                 \
    float cy_ = __fadd_rn(ACC[1], (BIAS));                                 \
    LIF2(M, cx_, cy_, BETA, THR);                                          \
    u64 b0_ = __ballot(__fsub_rn(M[0], (THR)) > 0.0f);                     \
    u64 b1_ = __ballot(__fsub_rn(M[1], (THR)) > 0.0f);                     \
    MA = __builtin_amdgcn_readfirstlane((unsigned)b0_);                    \
    MB = __builtin_amdgcn_readfirstlane((unsigned)b1_); }

// hidden layer: 32 inputs, quad-j b128 weight reads split into two f32x2 pairs
#define HLAYER(ACC, LBASE, MA, MB) {                                       \
    _Pragma("unroll")                                                      \
    for (int jq_ = 0; jq_ < 8; ++jq_) {                                    \
      f32x4 w4_ = whq4[(LBASE) + jq_ * 32 + i32];                          \
      f32x2 wl_ = {w4_[0], w4_[1]};                                        \
      f32x2 wh_ = {w4_[2], w4_[3]};                                        \
      u64 s0_ = SEL2(MA, MB, 4 * jq_ + 0);                                 \
      u64 s1_ = SEL2(MA, MB, 4 * jq_ + 1);                                 \
      u64 s2_ = SEL2(MA, MB, 4 * jq_ + 2);                                 \
      u64 s3_ = SEL2(MA, MB, 4 * jq_ + 3);                                 \
      PKFMA_SLO(ACC, s0_, wl_); PKFMA_SHI(ACC, s1_, wl_);                  \
      PKFMA_SLO(ACC, s2_, wh_); PKFMA_SHI(ACC, s3_, wh_);                  \
    } }

extern "C" __global__ __launch_bounds__(1024, 1)
void snn_actor_critic(const float* __restrict__ inputs,
                      const float* __restrict__ Win, const float* __restrict__ bin_,
                      const float* __restrict__ W1,  const float* __restrict__ b1,
                      const float* __restrict__ W2,  const float* __restrict__ b2,
                      const float* __restrict__ W3,  const float* __restrict__ b3,
                      const float* __restrict__ W4,  const float* __restrict__ b4,
                      const float* __restrict__ W5,  const float* __restrict__ b5,
                      const float* __restrict__ W6,  const float* __restrict__ b6,
                      const float* __restrict__ W7,  const float* __restrict__ b7,
                      const float* __restrict__ Wa,  const float* __restrict__ ba,
                      const float* __restrict__ Wc,  const float* __restrict__ bc,
                      const float* __restrict__ betac, const float* __restrict__ am,
                      float* __restrict__ out)
{
  extern __shared__ float lds[];
  const int tid  = threadIdx.x;
  const int lane = tid & 63;
  const int i32  = lane & 31;
  const int wave = tid >> 6;

  f32x4* winq4w = (f32x4*)(lds + OFF_WINQ);
  f32x4* w1q4w  = (f32x4*)(lds + OFF_W1Q);
  f32x4* whq4w  = (f32x4*)(lds + OFF_WHQ);
  f32x4* waq4w  = (f32x4*)(lds + OFF_WAQ);
  f32x2* wcp2w  = (f32x2*)(lds + OFF_WCP);

  // ---- stage quad-j weight layouts ----
  { int jq = tid >> 6, l = tid & 63;                         // Win 64x64
    winq4w[tid] = (f32x4){Win[l*64+4*jq], Win[l*64+4*jq+1],
                          Win[l*64+4*jq+2], Win[l*64+4*jq+3]}; }
  if (tid < 512) { int jq = tid >> 5, i = tid & 31;          // W1 32x64
    w1q4w[tid] = (f32x4){W1[i*64+4*jq], W1[i*64+4*jq+1],
                         W1[i*64+4*jq+2], W1[i*64+4*jq+3]}; }
  { int L = tid >> 8, r = tid & 255, jq = r >> 5, i = r & 31; // W2..W5
    const float* W = (L==0) ? W2 : (L==1) ? W3 : (L==2) ? W4 : W5;
    whq4w[L*256 + jq*32 + i] = (f32x4){W[i*32+4*jq], W[i*32+4*jq+1],
                                       W[i*32+4*jq+2], W[i*32+4*jq+3]}; }
  if (tid < 512) { int L = tid >> 8, r = tid & 255, jq = r >> 5, i = r & 31; // W6,W7
    const float* W = L ? W7 : W6;
    whq4w[(L+4)*256 + jq*32 + i] = (f32x4){W[i*32+4*jq], W[i*32+4*jq+1],
                                           W[i*32+4*jq+2], W[i*32+4*jq+3]}; }
  for (int e = tid; e < 3584; e += 1024) {                   // W_actor 400x32
    int r = e >> 9, rem = e & 511, jq = rem >> 6, l = rem & 63;
    int k = r * 64 + l;
    waq4w[e] = (k < 400)
        ? (f32x4){Wa[k*32+4*jq], Wa[k*32+4*jq+1], Wa[k*32+4*jq+2], Wa[k*32+4*jq+3]}
        : (f32x4){0.0f, 0.0f, 0.0f, 0.0f};
  }
  if (tid < 16) wcp2w[tid] = (f32x2){Wc[2*tid], Wc[2*tid+1]};
  if (tid == 0) {                                            // 0.01f sequential sums
    float a = 0.0f; lds[OFF_TAB] = 0.0f; float step = am[0];
    for (int n = 1; n <= 100; ++n) { a = __fadd_rn(a, step); lds[OFF_TAB + n] = a; }
  }

  // ---- biases / consts ----
  float bin_f = bin_[lane];
  float bh0 = b1[i32], bh1 = b2[i32], bh2 = b3[i32], bh3 = b4[i32],
        bh4 = b5[i32], bh5 = b6[i32], bh6 = b7[i32];
  float bA0 = ba[lane],       bA1 = ba[lane + 64],  bA2 = ba[lane + 128],
        bA3 = ba[lane + 192], bA4 = ba[lane + 256], bA5 = ba[lane + 320],
        bA6 = (lane < 16) ? ba[lane + 384] : 0.0f;
  float bc_f = bc[0];
  float beta_cf = betac[0];

  __syncthreads();

  // ---- role split: waves 0-7 hidden chain, waves 8-15 actor head ----
  const int  p   = wave & 7;                     // el-pair index in block
  const long e0  = (long)blockIdx.x * 16 + 2 * p;
  const f32x4* winq = (const f32x4*)(lds + OFF_WINQ);
  const f32x4* w1q  = (const f32x4*)(lds + OFF_W1Q);
  const f32x4* whq4 = (const f32x4*)(lds + OFF_WHQ);
  const f32x4* waq4 = (const f32x4*)(lds + OFF_WAQ);
  const f32x2* wcp2 = (const f32x2*)(lds + OFF_WCP);
  const f32x2* xp   = (const f32x2*)(lds + OFF_XP) + p * 64;
  f32x2* xpw        = (f32x2*)(lds + OFF_XP) + p * 64;
  uint2* mskw       = (uint2*)(lds + OFF_MSK);
  const float* tab  = lds + OFF_TAB;
  const float* inp0 = inputs + e0 * 64 + lane;
  const float* inp1 = inputs + (e0 + 1) * 64 + lane;
  float* vout = out + e0;                                    // vals[t*B + e]
  float* aout = out + (long)TSTEPS * BATCH + e0 * 4;         // actions[(t*B+e)*4+g]

  // hidden-wave state
  f32x2 mI = {0,0};
  f32x2 m1 = {0,0}, m2 = {0,0}, m3 = {0,0}, m4 = {0,0}, m5 = {0,0}, m6 = {0,0}, m7 = {0,0};
  f32x2 mc = {0,0};
  // actor-wave state
  f32x2 A0 = {0,0}, A1 = {0,0}, A2 = {0,0}, A3 = {0,0}, A4 = {0,0}, A5 = {0,0}, A6 = {0,0};

  float xn0 = inp0[0], xn1 = inp1[0];            // prefetch t=0

  for (int i = 0; i <= TSTEPS; ++i) {
    if (wave < 8) {
      if (i < TSTEPS) {
        const int t = i;
        xpw[lane] = (f32x2){xn0, xn1};
        if (t + 1 < TSTEPS) {
          xn0 = inp0[(long)(t + 1) * (BATCH * 64)];
          xn1 = inp1[(long)(t + 1) * (BATCH * 64)];
        }
        // ---- input layer: dense 64-dot, ascending j, pk over el-pair ----
        f32x2 aI = {0,0};
        #pragma unroll
        for (int jq = 0; jq < 16; ++jq) {
          f32x4 w4 = winq[jq * 64 + lane];
          f32x2 wl = {w4[0], w4[1]};
          f32x2 wh = {w4[2], w4[3]};
          f32x2 x0 = xp[4 * jq + 0], x1 = xp[4 * jq + 1],
                x2 = xp[4 * jq + 2], x3 = xp[4 * jq + 3];
          PKFMA_VLO(aI, x0, wl); PKFMA_VHI(aI, x1, wl);
          PKFMA_VLO(aI, x2, wh); PKFMA_VHI(aI, x3, wh);
        }
        { float cx = __fadd_rn(aI[0], bin_f), cy = __fadd_rn(aI[1], bin_f);
          LIF2(mI, cx, cy, 0.65f, 0.25f); }
        u64 ib0 = __ballot(__fsub_rn(mI[0], 0.25f) > 0.0f);
        u64 ib1 = __ballot(__fsub_rn(mI[1], 0.25f) > 0.0f);
        unsigned s0lo = __builtin_amdgcn_readfirstlane((unsigned)ib0);
        unsigned s0hi = __builtin_amdgcn_readfirstlane((unsigned)(ib0 >> 32));
        unsigned s1lo = __builtin_amdgcn_readfirstlane((unsigned)ib1);
        unsigned s1hi = __builtin_amdgcn_readfirstlane((unsigned)(ib1 >> 32));

        // ---- L1: 64 spike inputs -> 32 neurons ----
        f32x2 a1 = {0,0};
        #pragma unroll
        for (int jq = 0; jq < 16; ++jq) {
          f32x4 w4 = w1q[jq * 32 + i32];
          f32x2 wl = {w4[0], w4[1]};
          f32x2 wh = {w4[2], w4[3]};
          unsigned ma = (jq < 8) ? s0lo : s0hi;
          unsigned mb = (jq < 8) ? s1lo : s1hi;
          int jb = (4 * jq) & 31;
          u64 s0 = SEL2(ma, mb, jb + 0);
          u64 s1 = SEL2(ma, mb, jb + 1);
          u64 s2 = SEL2(ma, mb, jb + 2);
          u64 s3 = SEL2(ma, mb, jb + 3);
          PKFMA_SLO(a1, s0, wl); PKFMA_SHI(a1, s1, wl);
          PKFMA_SLO(a1, s2, wh); PKFMA_SHI(a1, s3, wh);
        }
        unsigned k1a, k1b; SPIKES32(m1, a1, bh0, 0.65f, 0.25f, k1a, k1b);

        // ---- L2..L7 ----
        f32x2 a2 = {0,0}; HLAYER(a2, 0 * 256, k1a, k1b);
        unsigned k2a, k2b; SPIKES32(m2, a2, bh1, 0.85f, 1.0f, k2a, k2b);
        f32x2 a3 = {0,0}; HLAYER(a3, 1 * 256, k2a, k2b);
        unsigned k3a, k3b; SPIKES32(m3, a3, bh2, 0.85f, 1.0f, k3a, k3b);
        f32x2 a4 = {0,0}; HLAYER(a4, 2 * 256, k3a, k3b);
        unsigned k4a, k4b; SPIKES32(m4, a4, bh3, 0.95f, 1.0f, k4a, k4b);
        f32x2 a5 = {0,0}; HLAYER(a5, 3 * 256, k4a, k4b);
        unsigned k5a, k5b; SPIKES32(m5, a5, bh4, 0.95f, 1.0f, k5a, k5b);
        f32x2 a6 = {0,0}; HLAYER(a6, 4 * 256, k5a, k5b);
        unsigned k6a, k6b; SPIKES32(m6, a6, bh5, 0.95f, 1.0f, k6a, k6b);
        f32x2 a7 = {0,0}; HLAYER(a7, 5 * 256, k6a, k6b);
        unsigned k7a, k7b; SPIKES32(m7, a7, bh6, 0.95f, 1.0f, k7a, k7b);

        // ---- critic ----
        f32x2 ac = {0,0};
        #pragma unroll
        for (int jp = 0; jp < 16; ++jp) {
          f32x2 wc2 = wcp2[jp];
          u64 sA = SEL2(k7a, k7b, 2 * jp);
          u64 sB = SEL2(k7a, k7b, 2 * jp + 1);
          PKFMA_SLO(ac, sA, wc2);
          PKFMA_SHI(ac, sB, wc2);
        }
        { float cx = __fadd_rn(ac[0], bc_f), cy = __fadd_rn(ac[1], bc_f);
          LIF2(mc, cx, cy, beta_cf, 100.0f); }
        if (lane < 2) vout[(long)t * BATCH + lane] = lane ? mc[1] : mc[0];
        if (lane == 0) mskw[(t & 1) * 8 + p] = (uint2){k7a, k7b};
      }
    } else {
      if (i > 0) {
        const int t = i - 1;
        uint2 mm = mskw[(t & 1) * 8 + p];
        unsigned k7a = __builtin_amdgcn_readfirstlane(mm.x);
        unsigned k7b = __builtin_amdgcn_readfirstlane(mm.y);

        // ---- actor: 400 outputs, 7 rows/lane, shared sels over quad-j ----
        f32x2 c0 = {0,0}, c1 = {0,0}, c2 = {0,0}, c3 = {0,0},
              c4 = {0,0}, c5 = {0,0}, c6 = {0,0};
        #pragma unroll
        for (int jq = 0; jq < 8; ++jq) {
          f32x4 q0 = waq4[0 * 512 + jq * 64 + lane];
          f32x4 q1 = waq4[1 * 512 + jq * 64 + lane];
          f32x4 q2 = waq4[2 * 512 + jq * 64 + lane];
          f32x4 q3 = waq4[3 * 512 + jq * 64 + lane];
          f32x4 q4 = waq4[4 * 512 + jq * 64 + lane];
          f32x4 q5 = waq4[5 * 512 + jq * 64 + lane];
          f32x4 q6 = waq4[6 * 512 + jq * 64 + lane];
          u64 s0 = SEL2(k7a, k7b, 4 * jq + 0);
          u64 s1 = SEL2(k7a, k7b, 4 * jq + 1);
          u64 s2 = SEL2(k7a, k7b, 4 * jq + 2);
          u64 s3 = SEL2(k7a, k7b, 4 * jq + 3);
          f32x2 wl, wh;
          wl = (f32x2){q0[0], q0[1]}; wh = (f32x2){q0[2], q0[3]};
          PKFMA_SLO(c0, s0, wl); PKFMA_SHI(c0, s1, wl);
          PKFMA_SLO(c0, s2, wh); PKFMA_SHI(c0, s3, wh);
          wl = (f32x2){q1[0], q1[1]}; wh = (f32x2){q1[2], q1[3]};
          PKFMA_SLO(c1, s0, wl); PKFMA_SHI(c1, s1, wl);
          PKFMA_SLO(c1, s2, wh); PKFMA_SHI(c1, s3, wh);
          wl = (f32x2){q2[0], q2[1]}; wh = (f32x2){q2[2], q2[3]};
          PKFMA_SLO(c2, s0, wl); PKFMA_SHI(c2, s1, wl);
          PKFMA_SLO(c2, s2, wh); PKFMA_SHI(c2, s3, wh);
          wl = (f32x2){q3[0], q3[1]}; wh = (f32x2){q3[2], q3[3]};
          PKFMA_SLO(c3, s0, wl); PKFMA_SHI(c3, s1, wl);
          PKFMA_SLO(c3, s2, wh); PKFMA_SHI(c3, s3, wh);
          wl = (f32x2){q4[0], q4[1]}; wh = (f32x2){q4[2], q4[3]};
          PKFMA_SLO(c4, s0, wl); PKFMA_SHI(c4, s1, wl);
          PKFMA_SLO(c4, s2, wh); PKFMA_SHI(c4, s3, wh);
          wl = (f32x2){q5[0], q5[1]}; wh = (f32x2){q5[2], q5[3]};
          PKFMA_SLO(c5, s0, wl); PKFMA_SHI(c5, s1, wl);
          PKFMA_SLO(c5, s2, wh); PKFMA_SHI(c5, s3, wh);
          wl = (f32x2){q6[0], q6[1]}; wh = (f32x2){q6[2], q6[3]};
          PKFMA_SLO(c6, s0, wl); PKFMA_SHI(c6, s1, wl);
          PKFMA_SLO(c6, s2, wh); PKFMA_SHI(c6, s3, wh);
        }
        u64 sa0, sa1, sa2, sa3, sa4, sa5, sa6;   // el0
        u64 ta0, ta1, ta2, ta3, ta4, ta5, ta6;   // el1
        {
          float cx, cy;
          cx = __fadd_rn(c0[0], bA0); cy = __fadd_rn(c0[1], bA0);
          LIF2(A0, cx, cy, 0.95f, 1.0f);
          sa0 = __ballot(__fsub_rn(A0[0], 1.0f) > 0.0f);
          ta0 = __ballot(__fsub_rn(A0[1], 1.0f) > 0.0f);
          cx = __fadd_rn(c1[0], bA1); cy = __fadd_rn(c1[1], bA1);
          LIF2(A1, cx, cy, 0.95f, 1.0f);
          sa1 = __ballot(__fsub_rn(A1[0], 1.0f) > 0.0f);
          ta1 = __ballot(__fsub_rn(A1[1], 1.0f) > 0.0f);
          cx = __fadd_rn(c2[0], bA2); cy = __fadd_rn(c2[1], bA2);
          LIF2(A2, cx, cy, 0.95f, 1.0f);
          sa2 = __ballot(__fsub_rn(A2[0], 1.0f) > 0.0f);
          ta2 = __ballot(__fsub_rn(A2[1], 1.0f) > 0.0f);
          cx = __fadd_rn(c3[0], bA3); cy = __fadd_rn(c3[1], bA3);
          LIF2(A3, cx, cy, 0.95f, 1.0f);
          sa3 = __ballot(__fsub_rn(A3[0], 1.0f) > 0.0f);
          ta3 = __ballot(__fsub_rn(A3[1], 1.0f) > 0.0f);
          cx = __fadd_rn(c4[0], bA4); cy = __fadd_rn(c4[1], bA4);
          LIF2(A4, cx, cy, 0.95f, 1.0f);
          sa4 = __ballot(__fsub_rn(A4[0], 1.0f) > 0.0f);
          ta4 = __ballot(__fsub_rn(A4[1], 1.0f) > 0.0f);
          cx = __fadd_rn(c5[0], bA5); cy = __fadd_rn(c5[1], bA5);
          LIF2(A5, cx, cy, 0.95f, 1.0f);
          sa5 = __ballot(__fsub_rn(A5[0], 1.0f) > 0.0f);
          ta5 = __ballot(__fsub_rn(A5[1], 1.0f) > 0.0f);
          cx = __fadd_rn(c6[0], bA6); cy = __fadd_rn(c6[1], bA6);
          LIF2(A6, cx, cy, 0.95f, 1.0f);
          sa6 = __ballot(__fsub_rn(A6[0], 1.0f) > 0.0f);
          ta6 = __ballot(__fsub_rn(A6[1], 1.0f) > 0.0f);
        }
        // group counts (neuron k = 64r + bit, group = k/100), per element
        int g0 = __popcll(sa0) + __popcll(sa1 & 0xFFFFFFFFFULL);
        int g1 = __popcll(sa1 >> 36) + __popcll(sa2) + __popcll(sa3 & 0xFFULL);
        int g2 = __popcll(sa3 >> 8) + __popcll(sa4 & 0xFFFFFFFFFFFULL);
        int g3 = __popcll(sa4 >> 44) + __popcll(sa5) + __popcll(sa6 & 0xFFFFULL);
        int h0 = __popcll(ta0) + __popcll(ta1 & 0xFFFFFFFFFULL);
        int h1 = __popcll(ta1 >> 36) + __popcll(ta2) + __popcll(ta3 & 0xFFULL);
        int h2 = __popcll(ta3 >> 8) + __popcll(ta4 & 0xFFFFFFFFFFFULL);
        int h3 = __popcll(ta4 >> 44) + __popcll(ta5) + __popcll(ta6 & 0xFFFFULL);

        if (lane < 8) {
          int g = lane & 3;
          int cnt = (lane >= 4) ? (g == 0 ? h0 : g == 1 ? h1 : g == 2 ? h2 : h3)
                                : (g == 0 ? g0 : g == 1 ? g1 : g == 2 ? g2 : g3);
          aout[(long)t * (BATCH * 4) + lane] = tab[cnt];
        }
      }
    }
    __syncthreads();
  }
}

extern "C" void kernel_launch(void* const* d_in, const int* in_sizes, int n_in,
                              void* d_out, int out_size, void* d_ws, size_t ws_size,
                              hipStream_t stream) {
  (void)in_sizes; (void)n_in; (void)out_size; (void)d_ws; (void)ws_size;
  hipFuncSetAttribute((const void*)snn_actor_critic,
                      hipFuncAttributeMaxDynamicSharedMemorySize, LDS_BYTES);
  const float* I    = (const float*)d_in[0];
  const float* Win  = (const float*)d_in[1];  const float* bin_ = (const float*)d_in[2];
  const float* W1   = (const float*)d_in[3];  const float* b1   = (const float*)d_in[4];
  const float* W2   = (const float*)d_in[5];  const float* b2   = (const float*)d_in[6];
  const float* W3   = (const float*)d_in[7];  const float* b3   = (const float*)d_in[8];
  const float* W4   = (const float*)d_in[9];  const float* b4   = (const float*)d_in[10];
  const float* W5   = (const float*)d_in[11]; const float* b5   = (const float*)d_in[12];
  const float* W6   = (const float*)d_in[13]; const float* b6   = (const float*)d_in[14];
  const float* W7   = (const float*)d_in[15]; const float* b7   = (const float*)d_in[16];
  const float* Wa   = (const float*)d_in[17]; const float* ba   = (const float*)d_in[18];
  const float* Wc   = (const float*)d_in[19]; const float* bc   = (const float*)d_in[20];
  const float* betc = (const float*)d_in[21]; const float* am   = (const float*)d_in[22];
  float* out = (float*)d_out;

  snn_actor_critic<<<dim3(BATCH / 16), dim3(1024), LDS_BYTES, stream>>>(
      I, Win, bin_, W1, b1, W2, b2, W3, b3, W4, b4, W5, b5, W6, b6, W7, b7,
      Wa, ba, Wc, bc, betc, am, out);
}

// Round 8
// 1024.498 us; speedup vs baseline: 1.5005x; 1.0452x over previous
//
#include <hip/hip_runtime.h>

#define TSTEPS 128
#define BATCH  4096

typedef float f32x2 __attribute__((ext_vector_type(2)));
typedef float f32x4 __attribute__((ext_vector_type(4)));
typedef unsigned long long u64;

// ---- LDS layout (f32 units) ----
#define OFF_WINQ 0        // [16 jq][64 l] f32x4          -> 4096
#define OFF_W1Q  4096     // [16 jq][32 i] f32x4          -> 2048
#define OFF_WHQ  6144     // 6 x [8 jq][32 i] f32x4       -> 6144
#define OFF_WAQ  12288    // [7 r][8 jq][64 l] f32x4      -> 14336
#define OFF_WCP  26624    // [16 jp] f32x2                -> 32
#define OFF_XP   26656    // 8 pairs x [64 j] f32x2       -> 1024
#define OFF_MSK  27680    // 2 slots x 8 pairs x uint2    -> 32
#define OFF_TAB  27712    // 101-entry sequential 0.01f sums
#define LDS_FLOATS 27816
#define LDS_BYTES  (LDS_FLOATS * 4)

// packed sel constants for the ACTOR path (el0, el1 halves, 1.0f patterns)
#define C00 0ull
#define C10 0x3f800000ull
#define C01 (0x3f800000ull << 32)
#define C11 (0x3f800000ull | (0x3f800000ull << 32))
#define SEL2(M0, M1, J)                                                    \
  ((((M0) >> (J)) & 1u) ? ((((M1) >> (J)) & 1u) ? C11 : C10)               \
                        : ((((M1) >> (J)) & 1u) ? C01 : C00))

// v_pk_fma_f32 (ACTOR + input layer): per-half IEEE f32 fma.
#define PKFMA_SLO(ACC, SEL, W2)                                            \
  asm("v_pk_fma_f32 %0, %1, %2, %0 op_sel:[0,0,0] op_sel_hi:[1,0,1]"       \
      : "+v"(ACC) : "s"(SEL), "v"(W2))
#define PKFMA_SHI(ACC, SEL, W2)                                            \
  asm("v_pk_fma_f32 %0, %1, %2, %0 op_sel:[0,1,0] op_sel_hi:[1,1,1]"       \
      : "+v"(ACC) : "s"(SEL), "v"(W2))
#define PKFMA_VLO(ACC, XY, W2)                                             \
  asm("v_pk_fma_f32 %0, %1, %2, %0 op_sel:[0,0,0] op_sel_hi:[1,0,1]"       \
      : "+v"(ACC) : "v"(XY), "v"(W2))
#define PKFMA_VHI(ACC, XY, W2)                                             \
  asm("v_pk_fma_f32 %0, %1, %2, %0 op_sel:[0,1,0] op_sel_hi:[1,1,1]"       \
      : "+v"(ACC) : "v"(XY), "v"(W2))

// ---- VALU sel path (hidden layers): ballot -> per-lane {0.0,1.0} vector ----
// lane j holds spike_j as float; 1 VALU per layer per element.
#define BITVEC(VF, MASK64)                                                 \
  asm("v_cndmask_b32 %0, 0, 1.0, %1" : "=v"(VF) : "s"(MASK64))
// uniform sel for term J: readlane (VALU) -> SGPR, feeds v_fmac directly
#define RLSEL(VF, J)                                                       \
  __int_as_float(__builtin_amdgcn_readlane(__float_as_int(VF), (J)))

// strict-f32 LIF (both elements), reset from PREVIOUS mem, per-op rounding
#define LIF2(M, CX, CY, BETA, THR) {                                       \
    float rx_ = (M[0] > (THR)) ? (THR) : 0.0f;                             \
    float ry_ = (M[1] > (THR)) ? (THR) : 0.0f;                             \
    M[0] = __fsub_rn(__fadd_rn(__fmul_rn((BETA), M[0]), (CX)), rx_);       \
    M[1] = __fsub_rn(__fadd_rn(__fmul_rn((BETA), M[1]), (CY)), ry_); }

// scalar-acc spike layer epilogue: LIF + two ballots (64-bit, halves mirrored)
#define SPIKB(MM, ACCA, ACCB, BIAS, BETA, THR, BA, BB) {                   \
    float ca_ = __fadd_rn(ACCA, (BIAS));                                   \
    float cb_ = __fadd_rn(ACCB, (BIAS));                                   \
    LIF2(MM, ca_, cb_, BETA, THR);                                         \
    BA = __ballot(__fsub_rn(MM[0], (THR)) > 0.0f);                         \
    BB = __ballot(__fsub_rn(MM[1], (THR)) > 0.0f); }

// hidden 32-input layer: quad-j b128 weight reads, readlane sels, 2 els
#define HLAYER_RL(ACCA, ACCB, LBASE, VA, VB) {                             \
    _Pragma("unroll")                                                      \
    for (int jq_ = 0; jq_ < 8; ++jq_) {                                    \
      f32x4 w4_ = whq4[(LBASE) + jq_ * 32 + i32];                          \
      _Pragma("unroll")                                                    \
      for (int jj_ = 0; jj_ < 4; ++jj_) {                                  \
        float sa_ = RLSEL(VA, 4 * jq_ + jj_);                              \
        float sb_ = RLSEL(VB, 4 * jq_ + jj_);                              \
        ACCA = __builtin_fmaf(sa_, w4_[jj_], ACCA);                        \
        ACCB = __builtin_fmaf(sb_, w4_[jj_], ACCB);                        \
      } } }

extern "C" __global__ __launch_bounds__(1024, 1)
void snn_actor_critic(const float* __restrict__ inputs,
                      const float* __restrict__ Win, const float* __restrict__ bin_,
                      const float* __restrict__ W1,  const float* __restrict__ b1,
                      const float* __restrict__ W2,  const float* __restrict__ b2,
                      const float* __restrict__ W3,  const float* __restrict__ b3,
                      const float* __restrict__ W4,  const float* __restrict__ b4,
                      const float* __restrict__ W5,  const float* __restrict__ b5,
                      const float* __restrict__ W6,  const float* __restrict__ b6,
                      const float* __restrict__ W7,  const float* __restrict__ b7,
                      const float* __restrict__ Wa,  const float* __restrict__ ba,
                      const float* __restrict__ Wc,  const float* __restrict__ bc,
                      const float* __restrict__ betac, const float* __restrict__ am,
                      float* __restrict__ out)
{
  extern __shared__ float lds[];
  const int tid  = threadIdx.x;
  const int lane = tid & 63;
  const int i32  = lane & 31;
  const int wave = tid >> 6;

  f32x4* winq4w = (f32x4*)(lds + OFF_WINQ);
  f32x4* w1q4w  = (f32x4*)(lds + OFF_W1Q);
  f32x4* whq4w  = (f32x4*)(lds + OFF_WHQ);
  f32x4* waq4w  = (f32x4*)(lds + OFF_WAQ);
  f32x2* wcp2w  = (f32x2*)(lds + OFF_WCP);

  // ---- stage quad-j weight layouts ----
  { int jq = tid >> 6, l = tid & 63;                         // Win 64x64
    winq4w[tid] = (f32x4){Win[l*64+4*jq], Win[l*64+4*jq+1],
                          Win[l*64+4*jq+2], Win[l*64+4*jq+3]}; }
  if (tid < 512) { int jq = tid >> 5, i = tid & 31;          // W1 32x64
    w1q4w[tid] = (f32x4){W1[i*64+4*jq], W1[i*64+4*jq+1],
                         W1[i*64+4*jq+2], W1[i*64+4*jq+3]}; }
  { int L = tid >> 8, r = tid & 255, jq = r >> 5, i = r & 31; // W2..W5
    const float* W = (L==0) ? W2 : (L==1) ? W3 : (L==2) ? W4 : W5;
    whq4w[L*256 + jq*32 + i] = (f32x4){W[i*32+4*jq], W[i*32+4*jq+1],
                                       W[i*32+4*jq+2], W[i*32+4*jq+3]}; }
  if (tid < 512) { int L = tid >> 8, r = tid & 255, jq = r >> 5, i = r & 31; // W6,W7
    const float* W = L ? W7 : W6;
    whq4w[(L+4)*256 + jq*32 + i] = (f32x4){W[i*32+4*jq], W[i*32+4*jq+1],
                                           W[i*32+4*jq+2], W[i*32+4*jq+3]}; }
  for (int e = tid; e < 3584; e += 1024) {                   // W_actor 400x32
    int r = e >> 9, rem = e & 511, jq = rem >> 6, l = rem & 63;
    int k = r * 64 + l;
    waq4w[e] = (k < 400)
        ? (f32x4){Wa[k*32+4*jq], Wa[k*32+4*jq+1], Wa[k*32+4*jq+2], Wa[k*32+4*jq+3]}
        : (f32x4){0.0f, 0.0f, 0.0f, 0.0f};
  }
  if (tid < 16) wcp2w[tid] = (f32x2){Wc[2*tid], Wc[2*tid+1]};
  if (tid == 0) {                                            // 0.01f sequential sums
    float a = 0.0f; lds[OFF_TAB] = 0.0f; float step = am[0];
    for (int n = 1; n <= 100; ++n) { a = __fadd_rn(a, step); lds[OFF_TAB + n] = a; }
  }

  // ---- biases / consts ----
  float bin_f = bin_[lane];
  float bh0 = b1[i32], bh1 = b2[i32], bh2 = b3[i32], bh3 = b4[i32],
        bh4 = b5[i32], bh5 = b6[i32], bh6 = b7[i32];
  float bA0 = ba[lane],       bA1 = ba[lane + 64],  bA2 = ba[lane + 128],
        bA3 = ba[lane + 192], bA4 = ba[lane + 256], bA5 = ba[lane + 320],
        bA6 = (lane < 16) ? ba[lane + 384] : 0.0f;
  float bc_f = bc[0];
  float beta_cf = betac[0];

  __syncthreads();

  // ---- role split: waves 0-7 hidden chain, waves 8-15 actor head ----
  const int  p   = wave & 7;                     // el-pair index in block
  const long e0  = (long)blockIdx.x * 16 + 2 * p;
  const f32x4* winq = (const f32x4*)(lds + OFF_WINQ);
  const f32x4* w1q  = (const f32x4*)(lds + OFF_W1Q);
  const f32x4* whq4 = (const f32x4*)(lds + OFF_WHQ);
  const f32x4* waq4 = (const f32x4*)(lds + OFF_WAQ);
  const f32x2* wcp2 = (const f32x2*)(lds + OFF_WCP);
  const f32x2* xp   = (const f32x2*)(lds + OFF_XP) + p * 64;
  f32x2* xpw        = (f32x2*)(lds + OFF_XP) + p * 64;
  uint2* mskw       = (uint2*)(lds + OFF_MSK);
  const float* tab  = lds + OFF_TAB;
  const float* inp0 = inputs + e0 * 64 + lane;
  const float* inp1 = inputs + (e0 + 1) * 64 + lane;
  float* vout = out + e0;                                    // vals[t*B + e]
  float* aout = out + (long)TSTEPS * BATCH + e0 * 4;         // actions[(t*B+e)*4+g]

  // hidden-wave state
  f32x2 mI = {0,0};
  f32x2 m1 = {0,0}, m2 = {0,0}, m3 = {0,0}, m4 = {0,0}, m5 = {0,0}, m6 = {0,0}, m7 = {0,0};
  f32x2 mc = {0,0};
  // actor-wave state
  f32x2 A0 = {0,0}, A1 = {0,0}, A2 = {0,0}, A3 = {0,0}, A4 = {0,0}, A5 = {0,0}, A6 = {0,0};

  float xn0 = inp0[0], xn1 = inp1[0];            // prefetch t=0

  for (int i = 0; i <= TSTEPS; ++i) {
    if (wave < 8) {
      if (i < TSTEPS) {
        const int t = i;
        xpw[lane] = (f32x2){xn0, xn1};
        if (t + 1 < TSTEPS) {
          xn0 = inp0[(long)(t + 1) * (BATCH * 64)];
          xn1 = inp1[(long)(t + 1) * (BATCH * 64)];
        }
        // ---- input layer: dense 64-dot, pk over el-pair (value-based) ----
        f32x2 aI = {0,0};
        #pragma unroll
        for (int jq = 0; jq < 16; ++jq) {
          f32x4 w4 = winq[jq * 64 + lane];
          f32x2 wl = {w4[0], w4[1]};
          f32x2 wh = {w4[2], w4[3]};
          f32x2 x0 = xp[4 * jq + 0], x1 = xp[4 * jq + 1],
                x2 = xp[4 * jq + 2], x3 = xp[4 * jq + 3];
          PKFMA_VLO(aI, x0, wl); PKFMA_VHI(aI, x1, wl);
          PKFMA_VLO(aI, x2, wh); PKFMA_VHI(aI, x3, wh);
        }
        u64 ib0, ib1;
        SPIKB(mI, aI[0], aI[1], bin_f, 0.65f, 0.25f, ib0, ib1);

        // ---- L1: 64 spike inputs -> 32 neurons (readlane sels) ----
        float vA, vB;
        BITVEC(vA, ib0); BITVEC(vB, ib1);
        float d1a = 0.0f, d1b = 0.0f;
        #pragma unroll
        for (int jq = 0; jq < 16; ++jq) {
          f32x4 w4 = w1q[jq * 32 + i32];
          #pragma unroll
          for (int jj = 0; jj < 4; ++jj) {
            float sa = RLSEL(vA, 4 * jq + jj);
            float sb = RLSEL(vB, 4 * jq + jj);
            d1a = __builtin_fmaf(sa, w4[jj], d1a);
            d1b = __builtin_fmaf(sb, w4[jj], d1b);
          }
        }
        u64 kb0a, kb0b;
        SPIKB(m1, d1a, d1b, bh0, 0.65f, 0.25f, kb0a, kb0b);

        // ---- L2..L7 (readlane sels; ballots feed next layer directly) ----
        float a2a = 0.0f, a2b = 0.0f;
        BITVEC(vA, kb0a); BITVEC(vB, kb0b);
        HLAYER_RL(a2a, a2b, 0 * 256, vA, vB);
        u64 kb1a, kb1b; SPIKB(m2, a2a, a2b, bh1, 0.85f, 1.0f, kb1a, kb1b);

        float a3a = 0.0f, a3b = 0.0f;
        BITVEC(vA, kb1a); BITVEC(vB, kb1b);
        HLAYER_RL(a3a, a3b, 1 * 256, vA, vB);
        u64 kb2a, kb2b; SPIKB(m3, a3a, a3b, bh2, 0.85f, 1.0f, kb2a, kb2b);

        float a4a = 0.0f, a4b = 0.0f;
        BITVEC(vA, kb2a); BITVEC(vB, kb2b);
        HLAYER_RL(a4a, a4b, 2 * 256, vA, vB);
        u64 kb3a, kb3b; SPIKB(m4, a4a, a4b, bh3, 0.95f, 1.0f, kb3a, kb3b);

        float a5a = 0.0f, a5b = 0.0f;
        BITVEC(vA, kb3a); BITVEC(vB, kb3b);
        HLAYER_RL(a5a, a5b, 3 * 256, vA, vB);
        u64 kb4a, kb4b; SPIKB(m5, a5a, a5b, bh4, 0.95f, 1.0f, kb4a, kb4b);

        float a6a = 0.0f, a6b = 0.0f;
        BITVEC(vA, kb4a); BITVEC(vB, kb4b);
        HLAYER_RL(a6a, a6b, 4 * 256, vA, vB);
        u64 kb5a, kb5b; SPIKB(m6, a6a, a6b, bh5, 0.95f, 1.0f, kb5a, kb5b);

        float a7a = 0.0f, a7b = 0.0f;
        BITVEC(vA, kb5a); BITVEC(vB, kb5b);
        HLAYER_RL(a7a, a7b, 5 * 256, vA, vB);
        u64 kb6a, kb6b; SPIKB(m7, a7a, a7b, bh6, 0.95f, 1.0f, kb6a, kb6b);

        // ---- critic: 32 terms, readlane sels, b64 broadcast weights ----
        float v7A, v7B;
        BITVEC(v7A, kb6a); BITVEC(v7B, kb6b);
        float cca = 0.0f, ccb = 0.0f;
        #pragma unroll
        for (int jp = 0; jp < 16; ++jp) {
          f32x2 wc2 = wcp2[jp];
          float sa0 = RLSEL(v7A, 2 * jp),     sb0 = RLSEL(v7B, 2 * jp);
          cca = __builtin_fmaf(sa0, wc2[0], cca);
          ccb = __builtin_fmaf(sb0, wc2[0], ccb);
          float sa1 = RLSEL(v7A, 2 * jp + 1), sb1 = RLSEL(v7B, 2 * jp + 1);
          cca = __builtin_fmaf(sa1, wc2[1], cca);
          ccb = __builtin_fmaf(sb1, wc2[1], ccb);
        }
        { float cx = __fadd_rn(cca, bc_f), cy = __fadd_rn(ccb, bc_f);
          LIF2(mc, cx, cy, beta_cf, 100.0f); }
        if (lane < 2) vout[(long)t * BATCH + lane] = lane ? mc[1] : mc[0];

        // handoff k7 masks (32-bit, lo half) to actor waves
        unsigned k7a = __builtin_amdgcn_readfirstlane((unsigned)kb6a);
        unsigned k7b = __builtin_amdgcn_readfirstlane((unsigned)kb6b);
        if (lane == 0) mskw[(t & 1) * 8 + p] = (uint2){k7a, k7b};
      }
    } else {
      if (i > 0) {
        const int t = i - 1;
        uint2 mm = mskw[(t & 1) * 8 + p];
        unsigned k7a = __builtin_amdgcn_readfirstlane(mm.x);
        unsigned k7b = __builtin_amdgcn_readfirstlane(mm.y);

        // ---- actor: 400 outputs, 7 rows/lane, SALU sels shared over rows ----
        f32x2 c0 = {0,0}, c1 = {0,0}, c2 = {0,0}, c3 = {0,0},
              c4 = {0,0}, c5 = {0,0}, c6 = {0,0};
        #pragma unroll
        for (int jq = 0; jq < 8; ++jq) {
          f32x4 q0 = waq4[0 * 512 + jq * 64 + lane];
          f32x4 q1 = waq4[1 * 512 + jq * 64 + lane];
          f32x4 q2 = waq4[2 * 512 + jq * 64 + lane];
          f32x4 q3 = waq4[3 * 512 + jq * 64 + lane];
          f32x4 q4 = waq4[4 * 512 + jq * 64 + lane];
          f32x4 q5 = waq4[5 * 512 + jq * 64 + lane];
          f32x4 q6 = waq4[6 * 512 + jq * 64 + lane];
          u64 s0 = SEL2(k7a, k7b, 4 * jq + 0);
          u64 s1 = SEL2(k7a, k7b, 4 * jq + 1);
          u64 s2 = SEL2(k7a, k7b, 4 * jq + 2);
          u64 s3 = SEL2(k7a, k7b, 4 * jq + 3);
          f32x2 wl, wh;
          wl = (f32x2){q0[0], q0[1]}; wh = (f32x2){q0[2], q0[3]};
          PKFMA_SLO(c0, s0, wl); PKFMA_SHI(c0, s1, wl);
          PKFMA_SLO(c0, s2, wh); PKFMA_SHI(c0, s3, wh);
          wl = (f32x2){q1[0], q1[1]}; wh = (f32x2){q1[2], q1[3]};
          PKFMA_SLO(c1, s0, wl); PKFMA_SHI(c1, s1, wl);
          PKFMA_SLO(c1, s2, wh); PKFMA_SHI(c1, s3, wh);
          wl = (f32x2){q2[0], q2[1]}; wh = (f32x2){q2[2], q2[3]};
          PKFMA_SLO(c2, s0, wl); PKFMA_SHI(c2, s1, wl);
          PKFMA_SLO(c2, s2, wh); PKFMA_SHI(c2, s3, wh);
          wl = (f32x2){q3[0], q3[1]}; wh = (f32x2){q3[2], q3[3]};
          PKFMA_SLO(c3, s0, wl); PKFMA_SHI(c3, s1, wl);
          PKFMA_SLO(c3, s2, wh); PKFMA_SHI(c3, s3, wh);
          wl = (f32x2){q4[0], q4[1]}; wh = (f32x2){q4[2], q4[3]};
          PKFMA_SLO(c4, s0, wl); PKFMA_SHI(c4, s1, wl);
          PKFMA_SLO(c4, s2, wh); PKFMA_SHI(c4, s3, wh);
          wl = (f32x2){q5[0], q5[1]}; wh = (f32x2){q5[2], q5[3]};
          PKFMA_SLO(c5, s0, wl); PKFMA_SHI(c5, s1, wl);
          PKFMA_SLO(c5, s2, wh); PKFMA_SHI(c5, s3, wh);
          wl = (f32x2){q6[0], q6[1]}; wh = (f32x2){q6[2], q6[3]};
          PKFMA_SLO(c6, s0, wl); PKFMA_SHI(c6, s1, wl);
          PKFMA_SLO(c6, s2, wh); PKFMA_SHI(c6, s3, wh);
        }
        u64 sa0, sa1, sa2, sa3, sa4, sa5, sa6;   // el0
        u64 ta0, ta1, ta2, ta3, ta4, ta5, ta6;   // el1
        {
          float cx, cy;
          cx = __fadd_rn(c0[0], bA0); cy = __fadd_rn(c0[1], bA0);
          LIF2(A0, cx, cy, 0.95f, 1.0f);
          sa0 = __ballot(__fsub_rn(A0[0], 1.0f) > 0.0f);
          ta0 = __ballot(__fsub_rn(A0[1], 1.0f) > 0.0f);
          cx = __fadd_rn(c1[0], bA1); cy = __fadd_rn(c1[1], bA1);
          LIF2(A1, cx, cy, 0.95f, 1.0f);
          sa1 = __ballot(__fsub_rn(A1[0], 1.0f) > 0.0f);
          ta1 = __ballot(__fsub_rn(A1[1], 1.0f) > 0.0f);
          cx = __fadd_rn(c2[0], bA2); cy = __fadd_rn(c2[1], bA2);
          LIF2(A2, cx, cy, 0.95f, 1.0f);
          sa2 = __ballot(__fsub_rn(A2[0], 1.0f) > 0.0f);
          ta2 = __ballot(__fsub_rn(A2[1], 1.0f) > 0.0f);
          cx = __fadd_rn(c3[0], bA3); cy = __fadd_rn(c3[1], bA3);
          LIF2(A3, cx, cy, 0.95f, 1.0f);
          sa3 = __ballot(__fsub_rn(A3[0], 1.0f) > 0.0f);
          ta3 = __ballot(__fsub_rn(A3[1], 1.0f) > 0.0f);
          cx = __fadd_rn(c4[0], bA4); cy = __fadd_rn(c4[1], bA4);
          LIF2(A4, cx, cy, 0.95f, 1.0f);
          sa4 = __ballot(__fsub_rn(A4[0], 1.0f) > 0.0f);
          ta4 = __ballot(__fsub_rn(A4[1], 1.0f) > 0.0f);
          cx = __fadd_rn(c5[0], bA5); cy = __fadd_rn(c5[1], bA5);
          LIF2(A5, cx, cy, 0.95f, 1.0f);
          sa5 = __ballot(__fsub_rn(A5[0], 1.0f) > 0.0f);
          ta5 = __ballot(__fsub_rn(A5[1], 1.0f) > 0.0f);
          cx = __fadd_rn(c6[0], bA6); cy = __fadd_rn(c6[1], bA6);
          LIF2(A6, cx, cy, 0.95f, 1.0f);
          sa6 = __ballot(__fsub_rn(A6[0], 1.0f) > 0.0f);
          ta6 = __ballot(__fsub_rn(A6[1], 1.0f) > 0.0f);
        }
        // group counts (neuron k = 64r + bit, group = k/100), per element
        int g0 = __popcll(sa0) + __popcll(sa1 & 0xFFFFFFFFFULL);
        int g1 = __popcll(sa1 >> 36) + __popcll(sa2) + __popcll(sa3 & 0xFFULL);
        int g2 = __popcll(sa3 >> 8) + __popcll(sa4 & 0xFFFFFFFFFFFULL);
        int g3 = __popcll(sa4 >> 44) + __popcll(sa5) + __popcll(sa6 & 0xFFFFULL);
        int h0 = __popcll(ta0) + __popcll(ta1 & 0xFFFFFFFFFULL);
        int h1 = __popcll(ta1 >> 36) + __popcll(ta2) + __popcll(ta3 & 0xFFULL);
        int h2 = __popcll(ta3 >> 8) + __popcll(ta4 & 0xFFFFFFFFFFFULL);
        int h3 = __popcll(ta4 >> 44) + __popcll(ta5) + __popcll(ta6 & 0xFFFFULL);

        if (lane < 8) {
          int g = lane & 3;
          int cnt = (lane >= 4) ? (g == 0 ? h0 : g == 1 ? h1 : g == 2 ? h2 : h3)
                                : (g == 0 ? g0 : g == 1 ? g1 : g == 2 ? g2 : g3);
          aout[(long)t * (BATCH * 4) + lane] = tab[cnt];
        }
      }
    }
    __syncthreads();
  }
}

extern "C" void kernel_launch(void* const* d_in, const int* in_sizes, int n_in,
                              void* d_out, int out_size, void* d_ws, size_t ws_size,
                              hipStream_t stream) {
  (void)in_sizes; (void)n_in; (void)out_size; (void)d_ws; (void)ws_size;
  hipFuncSetAttribute((const void*)snn_actor_critic,
                      hipFuncAttributeMaxDynamicSharedMemorySize, LDS_BYTES);
  const float* I    = (const float*)d_in[0];
  const float* Win  = (const float*)d_in[1];  const float* bin_ = (const float*)d_in[2];
  const float* W1   = (const float*)d_in[3];  const float* b1   = (const float*)d_in[4];
  const float* W2   = (const float*)d_in[5];  const float* b2   = (const float*)d_in[6];
  const float* W3   = (const float*)d_in[7];  const float* b3   = (const float*)d_in[8];
  const float* W4   = (const float*)d_in[9];  const float* b4   = (const float*)d_in[10];
  const float* W5   = (const float*)d_in[11]; const float* b5   = (const float*)d_in[12];
  const float* W6   = (const float*)d_in[13]; const float* b6   = (const float*)d_in[14];
  const float* W7   = (const float*)d_in[15]; const float* b7   = (const float*)d_in[16];
  const float* Wa   = (const float*)d_in[17]; const float* ba   = (const float*)d_in[18];
  const float* Wc   = (const float*)d_in[19]; const float* bc   = (const float*)d_in[20];
  const float* betc = (const float*)d_in[21]; const float* am   = (const float*)d_in[22];
  float* out = (float*)d_out;

  snn_actor_critic<<<dim3(BATCH / 16), dim3(1024), LDS_BYTES, stream>>>(
      I, Win, bin_, W1, b1, W2, b2, W3, b3, W4, b4, W5, b5, W6, b6, W7, b7,
      Wa, ba, Wc, bc, betc, am, out);
}